// Round 3
// baseline (637.861 us; speedup 1.0000x reference)
//
#include <hip/hip_runtime.h>
#include <hip/hip_bf16.h>
#include <stdint.h>

#define N_NODES 4096
#define U_NODES 2048
#define R_REL 5
#define B_BASES 30
#define H0 500
#define H1 75
#define E_EDGES 262144
#define EPS_BN 1e-5f
#define K_DIM 4096
#define M_COLS 3000   // 5*500 (h) + 500 (x@root)
#define M_PAD 3072
#define NSEG (N_NODES*R_REL)  // 20480

typedef __attribute__((ext_vector_type(4))) float f32x4;
typedef __attribute__((ext_vector_type(8))) short bf16x8;

static __device__ __forceinline__ ushort bf16_bits(float f) {
    union { float f; uint32_t u; } c; c.f = f;
    uint32_t u = c.u;
    uint32_t r = (u + 0x7fffu + ((u >> 16) & 1u)) >> 16;   // RNE
    return (ushort)r;
}

static __device__ __forceinline__ float bf16_to_f(ushort u) {
    union { uint32_t u; float f; } c; c.u = ((uint32_t)u) << 16; return c.f;
}

static __device__ __forceinline__ void fma_u4(f32x4& s, float w, ushort4 v) {
    s.x += w * bf16_to_f(v.x); s.y += w * bf16_to_f(v.y);
    s.z += w * bf16_to_f(v.z); s.w += w * bf16_to_f(v.w);
}

static __device__ __forceinline__ void async_copy16(const ushort* g, ushort* l) {
    __builtin_amdgcn_global_load_lds((const __attribute__((address_space(1))) void*)g,
                                     (__attribute__((address_space(3))) void*)l,
                                     16, 0, 0);
}

// ---------------- x fp32 -> bf16 (+ zero cnt, folds the memset dispatch) ----------------
__global__ void k_convert_x(const float* __restrict__ x, ushort* __restrict__ xb,
                            int* __restrict__ cnt) {
    int gid = blockIdx.x * 256 + threadIdx.x;
    if (gid < NSEG) cnt[gid] = 0;
    int i = gid * 4;  // N*N divisible by 1024
    float4 v = *(const float4*)(x + i);
    ushort4 o;
    o.x = bf16_bits(v.x); o.y = bf16_bits(v.y);
    o.z = bf16_bits(v.z); o.w = bf16_bits(v.w);
    *(ushort4*)(xb + i) = o;
}

// ---------------- WallT[m][k] bf16, m = r*500+o (r<5: sum_b comp[r,b]*basis[b,k,o]; r=5: root[k,o]) ----------------
__global__ void k_make_wallT(const float* __restrict__ basis, const float* __restrict__ comp,
                             const float* __restrict__ root, ushort* __restrict__ wallT) {
    __shared__ float compl_[R_REL * B_BASES];
    __shared__ float T[32][33];
    int t = threadIdx.x;
    if (t < R_REL * B_BASES) compl_[t] = comp[t];
    __syncthreads();
    int k0 = blockIdx.x * 32, o0 = blockIdx.y * 32;
    int o_in = t & 31, k_in = t >> 5;      // k_in 0..7
    int o = o0 + o_in;
    bool ov = (o < H0);
    float acc[4][6];
    #pragma unroll
    for (int a = 0; a < 4; a++)
        #pragma unroll
        for (int r = 0; r < 6; r++) acc[a][r] = 0.f;
    for (int b = 0; b < B_BASES; b++) {
        float cw[5];
        #pragma unroll
        for (int r = 0; r < 5; r++) cw[r] = compl_[r * B_BASES + b];
        #pragma unroll
        for (int a = 0; a < 4; a++) {
            int k = k0 + a * 8 + k_in;
            float v = ov ? basis[(size_t)b * K_DIM * H0 + (size_t)k * H0 + o] : 0.f;
            #pragma unroll
            for (int r = 0; r < 5; r++) acc[a][r] += cw[r] * v;
        }
    }
    #pragma unroll
    for (int a = 0; a < 4; a++) {
        int k = k0 + a * 8 + k_in;
        acc[a][5] = ov ? root[(size_t)k * H0 + o] : 0.f;
    }
    for (int r = 0; r < 6; r++) {
        __syncthreads();
        #pragma unroll
        for (int a = 0; a < 4; a++) T[o_in][a * 8 + k_in] = acc[a][r];
        __syncthreads();
        int ro = t >> 5, ck = t & 31;
        #pragma unroll
        for (int a = 0; a < 4; a++) {
            int oo = ro + a * 8;
            int om = o0 + oo;
            if (om < H0) {
                int m = r * H0 + om;
                wallT[(size_t)m * K_DIM + k0 + ck] = bf16_bits(T[oo][ck]);
            }
        }
    }
}

// ---------------- GEMM: Hall(4096 x 3000 bf16) = xb(4096x4096 bf16) @ WallT^T ----------------
// 256x256 tile, BK=64, 8 waves (2Mx4N), 4 phases/K-tile, double-buffered 128 KiB LDS.
// CORRECTED vmcnt discipline vs R1: drain vmcnt(4) at ends of P1, P2, P4 (none at P3),
// so every drained half-tile was issued exactly 3 phases (~1200 cy) earlier.
// In-flight queue (2 loads per stage): a0',b0',b1',a1' round-robin; vmcnt(4) leaves
// the 2 newest stages in flight. Steady state = 4-8 loads outstanding, never drained to 0.
__global__ __launch_bounds__(512, 2) void k_gemm(const ushort* __restrict__ A,
                                                 const ushort* __restrict__ BT,
                                                 ushort* __restrict__ C) {
    __shared__ __align__(16) ushort lds[65536];   // A: [2][256][64] @0 ; B: same @32768
    const int tid  = threadIdx.x;
    const int lane = tid & 63;
    const int wave = tid >> 6;          // 0..7
    int bid = blockIdx.x;               // 192 blocks, 192%8==0 -> bijective XCD swizzle
    int wg  = (bid & 7) * 24 + (bid >> 3);
    const int m0 = (wg & 15) << 8;      // 16 m-tiles
    const int n0 = (wg >> 4) << 8;      // 12 n-tiles
    const int wm = (wave >> 2) << 7;    // 0 or 128
    const int wn = (wave & 3) << 6;     // 0,64,128,192

    const int sj = tid >> 3;            // 0..63
    const int sc = tid & 7;             // dest chunk
    const int sg = sc ^ (sj & 7);       // pre-swizzled source chunk (row&7 == sj&7 always)

    const ushort* Ab = A  + (size_t)m0 * K_DIM + (size_t)sg * 8;
    const ushort* Bb = BT + (size_t)n0 * K_DIM + (size_t)sg * 8;

    f32x4 acc[8][4];
    #pragma unroll
    for (int i = 0; i < 8; i++)
        #pragma unroll
        for (int j = 0; j < 4; j++) { f32x4 z = {0.f,0.f,0.f,0.f}; acc[i][j] = z; }

    auto stageA = [&](int pb, int h, int Tn) {
        #pragma unroll
        for (int i = 0; i < 2; i++) {
            const ushort* src = Ab + (size_t)(h * 64 + sj + 128 * i) * K_DIM + Tn * 64;
            ushort* dst = lds + pb * 16384 + h * 4096 + (wave << 9) + i * 8192;
            async_copy16(src, dst);
        }
    };
    auto stageB = [&](int pb, int h, int Tn) {
        #pragma unroll
        for (int i = 0; i < 2; i++) {
            int comb = sj + 64 * i;
            const ushort* src = Bb + (size_t)((comb >> 5) * 64 + h * 32 + (comb & 31)) * K_DIM + Tn * 64;
            int cb = (wave << 3) + 64 * i;  // wave-uniform combined base
            ushort* dst = lds + 32768 + pb * 16384 + ((cb >> 5) << 12) + (h << 11) + ((cb & 31) << 6);
            async_copy16(src, dst);
        }
    };
    auto readA = [&](int pb, int fm, int s) -> bf16x8 {
        int row = wm + fm * 16 + (lane & 15);
        int ch  = (s * 4 + (lane >> 4)) ^ (row & 7);
        return *(const bf16x8*)(lds + pb * 16384 + row * 64 + ch * 8);
    };
    auto readB = [&](int pb, int fn, int s) -> bf16x8 {
        int row = wn + fn * 16 + (lane & 15);
        int ch  = (s * 4 + (lane >> 4)) ^ (row & 7);
        return *(const bf16x8*)(lds + 32768 + pb * 16384 + row * 64 + ch * 8);
    };

    // ---- prologue: tile 0 into buf0 in canonical issue order a0,b0,b1,a1;
    // drain only the oldest 4 (a0,b0) — matches steady-state depth.
    stageA(0, 0, 0); stageB(0, 0, 0); stageB(0, 1, 0); stageA(0, 1, 0);
    asm volatile("s_waitcnt vmcnt(4)" ::: "memory");
    __builtin_amdgcn_s_barrier();
    asm volatile("" ::: "memory");

    bf16x8 a[4][2], b[4][2];

    for (int T = 0; T < 64; T++) {
        int pb = T & 1, qb = pb ^ 1;
        int Tn = (T + 1) & 63;          // last tile wraps: harmless dead prefetch, no OOB

        // ---- P1: quadrant (m-lo, n-lo). reads A0-3 + B0-1; stage a0' = A-h0(T+1);
        //      vmcnt(4) drains b1(T) (issued T-1.P3, 3 phases ago) -> ready for P2
        #pragma unroll
        for (int fm = 0; fm < 4; fm++) { a[fm][0] = readA(pb, fm, 0); a[fm][1] = readA(pb, fm, 1); }
        #pragma unroll
        for (int fn = 0; fn < 2; fn++) { b[fn][0] = readB(pb, fn, 0); b[fn][1] = readB(pb, fn, 1); }
        stageA(qb, 0, Tn);
        asm volatile("s_waitcnt vmcnt(4)" ::: "memory");
        __builtin_amdgcn_s_barrier();
        asm volatile("" ::: "memory");
        __builtin_amdgcn_s_setprio(1);
        #pragma unroll
        for (int fm = 0; fm < 4; fm++)
            #pragma unroll
            for (int fn = 0; fn < 2; fn++) {
                acc[fm][fn] = __builtin_amdgcn_mfma_f32_16x16x32_bf16(a[fm][0], b[fn][0], acc[fm][fn], 0, 0, 0);
                acc[fm][fn] = __builtin_amdgcn_mfma_f32_16x16x32_bf16(a[fm][1], b[fn][1], acc[fm][fn], 0, 0, 0);
            }
        __builtin_amdgcn_s_setprio(0);
        asm volatile("" ::: "memory");
        __builtin_amdgcn_s_barrier();
        asm volatile("" ::: "memory");

        // ---- P2: quadrant (m-lo, n-hi). reads B2-3 (from B-h1(T)); stage b0' = B-h0(T+1);
        //      vmcnt(4) drains a1(T) (issued T-1.P4, 3 phases ago) -> ready for P3
        #pragma unroll
        for (int fn = 2; fn < 4; fn++) { b[fn][0] = readB(pb, fn, 0); b[fn][1] = readB(pb, fn, 1); }
        stageB(qb, 0, Tn);
        asm volatile("s_waitcnt vmcnt(4)" ::: "memory");
        __builtin_amdgcn_s_barrier();
        asm volatile("" ::: "memory");
        __builtin_amdgcn_s_setprio(1);
        #pragma unroll
        for (int fm = 0; fm < 4; fm++)
            #pragma unroll
            for (int fn = 2; fn < 4; fn++) {
                acc[fm][fn] = __builtin_amdgcn_mfma_f32_16x16x32_bf16(a[fm][0], b[fn][0], acc[fm][fn], 0, 0, 0);
                acc[fm][fn] = __builtin_amdgcn_mfma_f32_16x16x32_bf16(a[fm][1], b[fn][1], acc[fm][fn], 0, 0, 0);
            }
        __builtin_amdgcn_s_setprio(0);
        asm volatile("" ::: "memory");
        __builtin_amdgcn_s_barrier();
        asm volatile("" ::: "memory");

        // ---- P3: quadrant (m-hi, n-hi). reads A4-7 (from A-h1(T), overwrite a);
        //      stage b1' = B-h1(T+1); NO vmcnt here
        #pragma unroll
        for (int fm = 0; fm < 4; fm++) { a[fm][0] = readA(pb, 4 + fm, 0); a[fm][1] = readA(pb, 4 + fm, 1); }
        stageB(qb, 1, Tn);
        asm volatile("" ::: "memory");
        __builtin_amdgcn_s_barrier();
        asm volatile("" ::: "memory");
        __builtin_amdgcn_s_setprio(1);
        #pragma unroll
        for (int fm = 0; fm < 4; fm++)
            #pragma unroll
            for (int fn = 2; fn < 4; fn++) {
                acc[4 + fm][fn] = __builtin_amdgcn_mfma_f32_16x16x32_bf16(a[fm][0], b[fn][0], acc[4 + fm][fn], 0, 0, 0);
                acc[4 + fm][fn] = __builtin_amdgcn_mfma_f32_16x16x32_bf16(a[fm][1], b[fn][1], acc[4 + fm][fn], 0, 0, 0);
            }
        __builtin_amdgcn_s_setprio(0);
        asm volatile("" ::: "memory");
        __builtin_amdgcn_s_barrier();
        asm volatile("" ::: "memory");

        // ---- P4: quadrant (m-hi, n-lo). no new reads; stage a1' = A-h1(T+1);
        //      vmcnt(4) drains a0',b0' (issued 3 phases ago) -> ready for T+1.P1
        stageA(qb, 1, Tn);
        asm volatile("s_waitcnt vmcnt(4)" ::: "memory");
        __builtin_amdgcn_s_barrier();
        asm volatile("" ::: "memory");
        __builtin_amdgcn_s_setprio(1);
        #pragma unroll
        for (int fm = 0; fm < 4; fm++)
            #pragma unroll
            for (int fn = 0; fn < 2; fn++) {
                acc[4 + fm][fn] = __builtin_amdgcn_mfma_f32_16x16x32_bf16(a[fm][0], b[fn][0], acc[4 + fm][fn], 0, 0, 0);
                acc[4 + fm][fn] = __builtin_amdgcn_mfma_f32_16x16x32_bf16(a[fm][1], b[fn][1], acc[4 + fm][fn], 0, 0, 0);
            }
        __builtin_amdgcn_s_setprio(0);
        asm volatile("" ::: "memory");
        __builtin_amdgcn_s_barrier();
        asm volatile("" ::: "memory");
    }

    // ---- epilogue
    const int col = lane & 15;
    const int rbase = (lane >> 4) * 4;
    #pragma unroll
    for (int fm = 0; fm < 8; fm++) {
        #pragma unroll
        for (int fn = 0; fn < 4; fn++) {
            int gn = n0 + wn + fn * 16 + col;
            if (gn < M_COLS) {
                #pragma unroll
                for (int r = 0; r < 4; r++) {
                    int gm = m0 + wm + fm * 16 + rbase + r;
                    C[(size_t)gm * M_COLS + gn] = bf16_bits(acc[fm][fn][r]);
                }
            }
        }
    }
}

// ---------------- CSR build ----------------
__global__ void k_count(const int* __restrict__ ei, const int* __restrict__ et, int* __restrict__ cnt) {
    int e = blockIdx.x * 256 + threadIdx.x;
    if (e < E_EDGES) {
        int dst = ei[E_EDGES + e];
        int r = et[e];
        atomicAdd(&cnt[dst * R_REL + r], 1);
    }
}

// single block; int4-vectorized loads/stores (80 ints per thread = 20 int4)
__global__ void k_scan(const int* __restrict__ cnt, int* __restrict__ offs, int* __restrict__ cursor) {
    __shared__ int part[256];
    int t = threadIdx.x;
    int4 buf[20];
    const int4* c4 = (const int4*)(cnt + t * 80);
    int s = 0;
    #pragma unroll
    for (int i = 0; i < 20; i++) { buf[i] = c4[i]; s += buf[i].x + buf[i].y + buf[i].z + buf[i].w; }
    part[t] = s;
    __syncthreads();
    for (int d = 1; d < 256; d <<= 1) {
        int v = (t >= d) ? part[t - d] : 0;
        __syncthreads();
        part[t] += v;
        __syncthreads();
    }
    int run = part[t] - s;   // exclusive prefix
    int4* o4 = (int4*)(offs + t * 80);
    int4* u4 = (int4*)(cursor + t * 80);
    #pragma unroll
    for (int i = 0; i < 20; i++) {
        int4 c = buf[i];
        int4 o;
        o.x = run; o.y = run + c.x; o.z = run + c.x + c.y; o.w = run + c.x + c.y + c.z;
        run += c.x + c.y + c.z + c.w;
        o4[i] = o; u4[i] = o;
    }
    if (t == 255) offs[NSEG] = run;
}

// fill emits packed (src<<3)|r plus per-edge weight 1/cnt[seg]
__global__ void k_fill(const int* __restrict__ ei, const int* __restrict__ et,
                       const int* __restrict__ offs, int* __restrict__ cursor,
                       int* __restrict__ edge_val, float* __restrict__ edge_w) {
    int e = blockIdx.x * 256 + threadIdx.x;
    if (e < E_EDGES) {
        int src = ei[e];
        int dst = ei[E_EDGES + e];
        int r = et[e];
        int seg = dst * R_REL + r;
        int pos = atomicAdd(&cursor[seg], 1);
        edge_val[pos] = (src << 3) | r;
        edge_w[pos] = 1.0f / (float)(offs[seg + 1] - offs[seg]);
    }
}

// ---------------- per-node aggregation, edge-parallel ----------------
__global__ __launch_bounds__(512) void k_agg(const ushort* __restrict__ C, const int* __restrict__ offs,
                      const int* __restrict__ edge_val, const float* __restrict__ edge_w,
                      const float* __restrict__ bias, float* __restrict__ feats) {
    __shared__ float sh[3][H0];
    int n = blockIdx.x;
    int t = threadIdx.x;
    int g = t >> 7;            // edge-group 0..3 (uniform per wave)
    int tt = t & 127;          // column lane
    bool act = (tt < 125);     // 125*4 = 500 columns
    int beg = offs[n * R_REL];
    int end = offs[n * R_REL + R_REL];
    int chunk = (end - beg + 3) >> 2;
    int e0 = beg + g * chunk;
    int e1 = e0 + chunk;
    if (e0 > end) e0 = end;
    if (e1 > end) e1 = end;

    f32x4 s0 = {0.f,0.f,0.f,0.f}, s1 = {0.f,0.f,0.f,0.f};
    f32x4 s2 = {0.f,0.f,0.f,0.f}, s3 = {0.f,0.f,0.f,0.f};
    const ushort* Ct = C + tt * 4;
    int e = e0;
    if (act) {
        for (; e + 3 < e1; e += 4) {
            int   v0 = edge_val[e],   v1 = edge_val[e+1], v2 = edge_val[e+2], v3 = edge_val[e+3];
            float w0 = edge_w[e],     w1 = edge_w[e+1],   w2 = edge_w[e+2],   w3 = edge_w[e+3];
            ushort4 a0 = *(const ushort4*)(Ct + (size_t)(v0 >> 3) * M_COLS + (v0 & 7) * H0);
            ushort4 a1 = *(const ushort4*)(Ct + (size_t)(v1 >> 3) * M_COLS + (v1 & 7) * H0);
            ushort4 a2 = *(const ushort4*)(Ct + (size_t)(v2 >> 3) * M_COLS + (v2 & 7) * H0);
            ushort4 a3 = *(const ushort4*)(Ct + (size_t)(v3 >> 3) * M_COLS + (v3 & 7) * H0);
            fma_u4(s0, w0, a0); fma_u4(s1, w1, a1); fma_u4(s2, w2, a2); fma_u4(s3, w3, a3);
        }
        for (; e < e1; e++) {
            int v = edge_val[e];
            float w = edge_w[e];
            ushort4 a = *(const ushort4*)(Ct + (size_t)(v >> 3) * M_COLS + (v & 7) * H0);
            fma_u4(s0, w, a);
        }
    }
    f32x4 acc = (s0 + s1) + (s2 + s3);
    if (g > 0 && act) *(f32x4*)&sh[g - 1][tt * 4] = acc;
    __syncthreads();
    if (g == 0 && act) {
        acc += *(const f32x4*)&sh[0][tt * 4];
        acc += *(const f32x4*)&sh[1][tt * 4];
        acc += *(const f32x4*)&sh[2][tt * 4];
        ushort4 v = *(const ushort4*)(C + (size_t)n * M_COLS + 5 * H0 + tt * 4);
        acc.x += bf16_to_f(v.x); acc.y += bf16_to_f(v.y);
        acc.z += bf16_to_f(v.z); acc.w += bf16_to_f(v.w);
        acc += *(const f32x4*)(bias + tt * 4);
        *(f32x4*)(feats + (size_t)n * H0 + tt * 4) = acc;
    }
}

// ---------------- FC (feats @ fc_w^T) + per-row BN + ReLU, 4 rows per block ----------------
__global__ __launch_bounds__(128) void k_fc_bn(const float* __restrict__ feats, const float* __restrict__ fcw,
                                               const float* __restrict__ gu, const float* __restrict__ bu,
                                               const float* __restrict__ gi, const float* __restrict__ bi,
                                               float* __restrict__ out) {
    __shared__ float fs[4][H0];
    __shared__ float z[4][80];
    int t = threadIdx.x;
    int row0 = blockIdx.x * 4;
    if (t < 125) {
        #pragma unroll
        for (int r = 0; r < 4; r++)
            *(f32x4*)&fs[r][t * 4] = *(const f32x4*)(feats + (size_t)(row0 + r) * H0 + t * 4);
    }
    __syncthreads();
    if (t < H1) {
        float a0 = 0.f, a1 = 0.f, a2 = 0.f, a3 = 0.f;
        const float* wr = fcw + (size_t)t * H0;
        for (int k = 0; k < H0; k += 4) {
            float4 w = *(const float4*)(wr + k);
            a0 += w.x * fs[0][k] + w.y * fs[0][k+1] + w.z * fs[0][k+2] + w.w * fs[0][k+3];
            a1 += w.x * fs[1][k] + w.y * fs[1][k+1] + w.z * fs[1][k+2] + w.w * fs[1][k+3];
            a2 += w.x * fs[2][k] + w.y * fs[2][k+1] + w.z * fs[2][k+2] + w.w * fs[2][k+3];
            a3 += w.x * fs[3][k] + w.y * fs[3][k+1] + w.z * fs[3][k+2] + w.w * fs[3][k+3];
        }
        z[0][t] = a0; z[1][t] = a1; z[2][t] = a2; z[3][t] = a3;
    }
    __syncthreads();
    int lane = t & 63, wave = t >> 6;   // 2 waves, each handles 2 rows
    #pragma unroll
    for (int rr = 0; rr < 2; rr++) {
        int r = wave * 2 + rr;
        int row = row0 + r;
        float a = (lane < H1) ? z[r][lane] : 0.f;
        float b2 = (lane < H1 - 64) ? z[r][64 + lane] : 0.f;
        float s1 = a + b2, s2 = a * a + b2 * b2;
        #pragma unroll
        for (int s = 32; s > 0; s >>= 1) { s1 += __shfl_xor(s1, s); s2 += __shfl_xor(s2, s); }
        float mean = s1 / (float)H1;
        float var = s2 / (float)H1 - mean * mean;
        float inv = 1.0f / sqrtf(var + EPS_BN);
        float gamma, beta;
        if (row < U_NODES) { gamma = gu[row];            beta = bu[row]; }
        else               { gamma = gi[row - U_NODES];  beta = bi[row - U_NODES]; }
        if (lane < H1) {
            float v = gamma * (a - mean) * inv + beta;
            out[(size_t)row * H1 + lane] = v > 0.f ? v : 0.f;
        }
        if (lane < H1 - 64) {
            float v = gamma * (b2 - mean) * inv + beta;
            out[(size_t)row * H1 + 64 + lane] = v > 0.f ? v : 0.f;
        }
    }
}

extern "C" void kernel_launch(void* const* d_in, const int* in_sizes, int n_in,
                              void* d_out, int out_size, void* d_ws, size_t ws_size,
                              hipStream_t stream) {
    (void)in_sizes; (void)n_in; (void)out_size; (void)ws_size;
    const float* x         = (const float*)d_in[0];
    const float* basis     = (const float*)d_in[1];
    const float* comp      = (const float*)d_in[2];
    const float* root      = (const float*)d_in[3];
    const float* bias_rgcn = (const float*)d_in[4];
    const float* fc_w      = (const float*)d_in[5];
    const float* gu        = (const float*)d_in[6];
    const float* bu        = (const float*)d_in[7];
    const float* gi        = (const float*)d_in[8];
    const float* bi        = (const float*)d_in[9];
    const int*   ei        = (const int*)d_in[10];
    const int*   et        = (const int*)d_in[11];
    float* out = (float*)d_out;

    char* ws = (char*)d_ws;
    size_t off = 0;
    auto carve = [&](size_t bytes) -> void* {
        void* p = ws + off;
        off += (bytes + 255) & ~(size_t)255;
        return p;
    };
    ushort* xb      = (ushort*)carve((size_t)N_NODES * K_DIM * 2);
    ushort* wallT   = (ushort*)carve((size_t)M_PAD * K_DIM * 2);
    ushort* hall    = (ushort*)carve((size_t)N_NODES * M_COLS * 2);
    float*  feats   = (float*) carve((size_t)N_NODES * H0 * 4);
    int*    cnt     = (int*)   carve((size_t)NSEG * 4);
    int*    offs    = (int*)   carve((size_t)(NSEG + 1) * 4);
    int*    cursor  = (int*)   carve((size_t)NSEG * 4);
    int*    edge_val= (int*)   carve((size_t)E_EDGES * 4);
    float*  edge_w  = (float*) carve((size_t)E_EDGES * 4);

    k_convert_x<<<16384, 256, 0, stream>>>(x, xb, cnt);
    k_make_wallT<<<dim3(128, 16), 256, 0, stream>>>(basis, comp, root, wallT);
    k_count<<<E_EDGES / 256, 256, 0, stream>>>(ei, et, cnt);
    k_scan<<<1, 256, 0, stream>>>(cnt, offs, cursor);
    k_fill<<<E_EDGES / 256, 256, 0, stream>>>(ei, et, offs, cursor, edge_val, edge_w);
    k_gemm<<<192, 512, 0, stream>>>(xb, wallT, hall);
    k_agg<<<N_NODES, 512, 0, stream>>>(hall, offs, edge_val, edge_w, bias_rgcn, feats);
    k_fc_bn<<<N_NODES / 4, 128, 0, stream>>>(feats, fc_w, gu, bu, gi, bi, out);
}

// Round 4
// 621.267 us; speedup vs baseline: 1.0267x; 1.0267x over previous
//
#include <hip/hip_runtime.h>
#include <hip/hip_bf16.h>
#include <stdint.h>

#define N_NODES 4096
#define U_NODES 2048
#define R_REL 5
#define B_BASES 30
#define H0 500
#define H1 75
#define E_EDGES 262144
#define EPS_BN 1e-5f
#define K_DIM 4096
#define M_COLS 3000   // 5*500 (h) + 500 (x@root)
#define M_PAD 3072
#define NSEG (N_NODES*R_REL)  // 20480

typedef __attribute__((ext_vector_type(4))) float f32x4;
typedef __attribute__((ext_vector_type(8))) short bf16x8;

static __device__ __forceinline__ ushort bf16_bits(float f) {
    union { float f; uint32_t u; } c; c.f = f;
    uint32_t u = c.u;
    uint32_t r = (u + 0x7fffu + ((u >> 16) & 1u)) >> 16;   // RNE
    return (ushort)r;
}

static __device__ __forceinline__ float bf16_to_f(ushort u) {
    union { uint32_t u; float f; } c; c.u = ((uint32_t)u) << 16; return c.f;
}

static __device__ __forceinline__ void fma_u4(f32x4& s, float w, ushort4 v) {
    s.x += w * bf16_to_f(v.x); s.y += w * bf16_to_f(v.y);
    s.z += w * bf16_to_f(v.z); s.w += w * bf16_to_f(v.w);
}

static __device__ __forceinline__ void async_copy16(const ushort* g, ushort* l) {
    __builtin_amdgcn_global_load_lds((const __attribute__((address_space(1))) void*)g,
                                     (__attribute__((address_space(3))) void*)l,
                                     16, 0, 0);
}

// ---------------- x fp32 -> bf16 (+ zero cnt, folds the memset dispatch) ----------------
__global__ void k_convert_x(const float* __restrict__ x, ushort* __restrict__ xb,
                            int* __restrict__ cnt) {
    int gid = blockIdx.x * 256 + threadIdx.x;
    if (gid < NSEG) cnt[gid] = 0;
    int i = gid * 4;  // N*N divisible by 1024
    float4 v = *(const float4*)(x + i);
    ushort4 o;
    o.x = bf16_bits(v.x); o.y = bf16_bits(v.y);
    o.z = bf16_bits(v.z); o.w = bf16_bits(v.w);
    *(ushort4*)(xb + i) = o;
}

// ---------------- WallT[m][k] bf16, m = r*500+o (r<5: sum_b comp[r,b]*basis[b,k,o]; r=5: root[k,o]) ----------------
__global__ void k_make_wallT(const float* __restrict__ basis, const float* __restrict__ comp,
                             const float* __restrict__ root, ushort* __restrict__ wallT) {
    __shared__ float compl_[R_REL * B_BASES];
    __shared__ float T[32][33];
    int t = threadIdx.x;
    if (t < R_REL * B_BASES) compl_[t] = comp[t];
    __syncthreads();
    int k0 = blockIdx.x * 32, o0 = blockIdx.y * 32;
    int o_in = t & 31, k_in = t >> 5;      // k_in 0..7
    int o = o0 + o_in;
    bool ov = (o < H0);
    float acc[4][6];
    #pragma unroll
    for (int a = 0; a < 4; a++)
        #pragma unroll
        for (int r = 0; r < 6; r++) acc[a][r] = 0.f;
    for (int b = 0; b < B_BASES; b++) {
        float cw[5];
        #pragma unroll
        for (int r = 0; r < 5; r++) cw[r] = compl_[r * B_BASES + b];
        #pragma unroll
        for (int a = 0; a < 4; a++) {
            int k = k0 + a * 8 + k_in;
            float v = ov ? basis[(size_t)b * K_DIM * H0 + (size_t)k * H0 + o] : 0.f;
            #pragma unroll
            for (int r = 0; r < 5; r++) acc[a][r] += cw[r] * v;
        }
    }
    #pragma unroll
    for (int a = 0; a < 4; a++) {
        int k = k0 + a * 8 + k_in;
        acc[a][5] = ov ? root[(size_t)k * H0 + o] : 0.f;
    }
    for (int r = 0; r < 6; r++) {
        __syncthreads();
        #pragma unroll
        for (int a = 0; a < 4; a++) T[o_in][a * 8 + k_in] = acc[a][r];
        __syncthreads();
        int ro = t >> 5, ck = t & 31;
        #pragma unroll
        for (int a = 0; a < 4; a++) {
            int oo = ro + a * 8;
            int om = o0 + oo;
            if (om < H0) {
                int m = r * H0 + om;
                wallT[(size_t)m * K_DIM + k0 + ck] = bf16_bits(T[oo][ck]);
            }
        }
    }
}

// ---------------- GEMM: Hall(4096 x 3000 bf16) = xb(4096x4096 bf16) @ WallT^T ----------------
// Verified 128x128 m97-structure: 768 blocks, 3 blocks/CU, ~912 TF class.
// LDS layout is XOR-swizzled: 16B chunk j of row r holds global chunk j^(r&7).
__global__ __launch_bounds__(256) void k_gemm(const ushort* __restrict__ A,
                                              const ushort* __restrict__ BT,
                                              ushort* __restrict__ C) {
    __shared__ __align__(16) ushort As[128 * 64];
    __shared__ __align__(16) ushort Bs[128 * 64];
    int tid = threadIdx.x;
    int lane = tid & 63, wave = tid >> 6;
    int bid = blockIdx.x;              // 768 linear
    int xcd = bid & 7;
    int j = bid >> 3;                  // 0..95
    int n_t = xcd * 3 + (j >> 5);      // 0..23
    int m_t = j & 31;                  // 0..31
    int m0 = m_t * 128, n0 = n_t * 128;
    int wm = (wave & 1) * 64, wn = (wave >> 1) * 64;

    f32x4 acc[4][4];
    #pragma unroll
    for (int a = 0; a < 4; a++)
        #pragma unroll
        for (int b = 0; b < 4; b++) { f32x4 z = {0.f, 0.f, 0.f, 0.f}; acc[a][b] = z; }

    int srow = tid >> 3;                                  // 0..31
    int skc = (((tid & 7) ^ ((tid >> 3) & 7))) * 8;      // XOR-swizzled k-chunk
    const ushort* Abase = A + (size_t)(m0 + srow) * K_DIM + skc;
    const ushort* Bbase = BT + (size_t)(n0 + srow) * K_DIM + skc;
    int ldsoff = (wave * 64) * 8; // wave-uniform LDS chunk base (in ushorts)

    for (int k0 = 0; k0 < K_DIM; k0 += 64) {
        const ushort* ga = Abase + k0;
        const ushort* gb = Bbase + k0;
        #pragma unroll
        for (int i = 0; i < 4; i++) {
            async_copy16(ga + (size_t)i * 32 * K_DIM, As + i * 2048 + ldsoff);
            async_copy16(gb + (size_t)i * 32 * K_DIM, Bs + i * 2048 + ldsoff);
        }
        __syncthreads();
        #pragma unroll
        for (int kk = 0; kk < 64; kk += 32) {
            bf16x8 af[4], bfr[4];
            int koff = kk + ((lane >> 4) * 8);
            int g = koff >> 3;                            // global chunk 0..7
            #pragma unroll
            for (int a = 0; a < 4; a++) {
                int row = wm + a * 16 + (lane & 15);
                int sw = (g ^ (row & 7)) * 8;
                af[a] = *(const bf16x8*)(As + row * 64 + sw);
            }
            #pragma unroll
            for (int b = 0; b < 4; b++) {
                int row = wn + b * 16 + (lane & 15);
                int sw = (g ^ (row & 7)) * 8;
                bfr[b] = *(const bf16x8*)(Bs + row * 64 + sw);
            }
            #pragma unroll
            for (int a = 0; a < 4; a++)
                #pragma unroll
                for (int b = 0; b < 4; b++)
                    acc[a][b] = __builtin_amdgcn_mfma_f32_16x16x32_bf16(af[a], bfr[b], acc[a][b], 0, 0, 0);
        }
        __syncthreads();
    }

    int col = lane & 15;
    int rbase = (lane >> 4) * 4;
    #pragma unroll
    for (int a = 0; a < 4; a++) {
        #pragma unroll
        for (int b = 0; b < 4; b++) {
            int gn = n0 + wn + b * 16 + col;
            if (gn < M_COLS) {
                #pragma unroll
                for (int r = 0; r < 4; r++) {
                    int gm = m0 + wm + a * 16 + rbase + r;
                    C[(size_t)gm * M_COLS + gn] = bf16_bits(acc[a][b][r]);
                }
            }
        }
    }
}

// ---------------- CSR build ----------------
__global__ void k_count(const int* __restrict__ ei, const int* __restrict__ et, int* __restrict__ cnt) {
    int e = blockIdx.x * 256 + threadIdx.x;
    if (e < E_EDGES) {
        int dst = ei[E_EDGES + e];
        int r = et[e];
        atomicAdd(&cnt[dst * R_REL + r], 1);
    }
}

// single block; int4-vectorized loads/stores (80 ints per thread = 20 int4)
__global__ void k_scan(const int* __restrict__ cnt, int* __restrict__ offs, int* __restrict__ cursor) {
    __shared__ int part[256];
    int t = threadIdx.x;
    int4 buf[20];
    const int4* c4 = (const int4*)(cnt + t * 80);
    int s = 0;
    #pragma unroll
    for (int i = 0; i < 20; i++) { buf[i] = c4[i]; s += buf[i].x + buf[i].y + buf[i].z + buf[i].w; }
    part[t] = s;
    __syncthreads();
    for (int d = 1; d < 256; d <<= 1) {
        int v = (t >= d) ? part[t - d] : 0;
        __syncthreads();
        part[t] += v;
        __syncthreads();
    }
    int run = part[t] - s;   // exclusive prefix
    int4* o4 = (int4*)(offs + t * 80);
    int4* u4 = (int4*)(cursor + t * 80);
    #pragma unroll
    for (int i = 0; i < 20; i++) {
        int4 c = buf[i];
        int4 o;
        o.x = run; o.y = run + c.x; o.z = run + c.x + c.y; o.w = run + c.x + c.y + c.z;
        run += c.x + c.y + c.z + c.w;
        o4[i] = o; u4[i] = o;
    }
    if (t == 255) offs[NSEG] = run;
}

// fill emits packed (src<<3)|r plus per-edge weight 1/cnt[seg]
__global__ void k_fill(const int* __restrict__ ei, const int* __restrict__ et,
                       const int* __restrict__ offs, int* __restrict__ cursor,
                       int* __restrict__ edge_val, float* __restrict__ edge_w) {
    int e = blockIdx.x * 256 + threadIdx.x;
    if (e < E_EDGES) {
        int src = ei[e];
        int dst = ei[E_EDGES + e];
        int r = et[e];
        int seg = dst * R_REL + r;
        int pos = atomicAdd(&cursor[seg], 1);
        edge_val[pos] = (src << 3) | r;
        edge_w[pos] = 1.0f / (float)(offs[seg + 1] - offs[seg]);
    }
}

// ---------------- per-node aggregation: one flat weighted loop over the node's edges ----------------
__global__ void k_agg(const ushort* __restrict__ C, const int* __restrict__ offs,
                      const int* __restrict__ edge_val, const float* __restrict__ edge_w,
                      const float* __restrict__ bias, float* __restrict__ feats) {
    int n = blockIdx.x;
    int t = threadIdx.x;
    if (t >= 125) return;      // 125 * 4 = 500 columns
    int beg = offs[n * R_REL];
    int end = offs[n * R_REL + R_REL];
    f32x4 s0 = {0.f,0.f,0.f,0.f}, s1 = {0.f,0.f,0.f,0.f};
    f32x4 s2 = {0.f,0.f,0.f,0.f}, s3 = {0.f,0.f,0.f,0.f};
    const ushort* Ct = C + t * 4;
    int e = beg;
    for (; e + 3 < end; e += 4) {
        int   v0 = edge_val[e],   v1 = edge_val[e+1], v2 = edge_val[e+2], v3 = edge_val[e+3];
        float w0 = edge_w[e],     w1 = edge_w[e+1],   w2 = edge_w[e+2],   w3 = edge_w[e+3];
        ushort4 a0 = *(const ushort4*)(Ct + (size_t)(v0 >> 3) * M_COLS + (v0 & 7) * H0);
        ushort4 a1 = *(const ushort4*)(Ct + (size_t)(v1 >> 3) * M_COLS + (v1 & 7) * H0);
        ushort4 a2 = *(const ushort4*)(Ct + (size_t)(v2 >> 3) * M_COLS + (v2 & 7) * H0);
        ushort4 a3 = *(const ushort4*)(Ct + (size_t)(v3 >> 3) * M_COLS + (v3 & 7) * H0);
        fma_u4(s0, w0, a0); fma_u4(s1, w1, a1); fma_u4(s2, w2, a2); fma_u4(s3, w3, a3);
    }
    for (; e < end; e++) {
        int v = edge_val[e];
        float w = edge_w[e];
        ushort4 a = *(const ushort4*)(Ct + (size_t)(v >> 3) * M_COLS + (v & 7) * H0);
        fma_u4(s0, w, a);
    }
    f32x4 acc = (s0 + s1) + (s2 + s3);
    {
        ushort4 v = *(const ushort4*)(C + (size_t)n * M_COLS + 5 * H0 + t * 4);
        acc.x += bf16_to_f(v.x); acc.y += bf16_to_f(v.y);
        acc.z += bf16_to_f(v.z); acc.w += bf16_to_f(v.w);
    }
    acc += *(const f32x4*)(bias + t * 4);
    *(f32x4*)(feats + (size_t)n * H0 + t * 4) = acc;
}

// ---------------- FC (feats @ fc_w^T) + per-row BN + ReLU, 4 rows per block ----------------
__global__ __launch_bounds__(128) void k_fc_bn(const float* __restrict__ feats, const float* __restrict__ fcw,
                                               const float* __restrict__ gu, const float* __restrict__ bu,
                                               const float* __restrict__ gi, const float* __restrict__ bi,
                                               float* __restrict__ out) {
    __shared__ float fs[4][H0];
    __shared__ float z[4][80];
    int t = threadIdx.x;
    int row0 = blockIdx.x * 4;
    if (t < 125) {
        #pragma unroll
        for (int r = 0; r < 4; r++)
            *(f32x4*)&fs[r][t * 4] = *(const f32x4*)(feats + (size_t)(row0 + r) * H0 + t * 4);
    }
    __syncthreads();
    if (t < H1) {
        float a0 = 0.f, a1 = 0.f, a2 = 0.f, a3 = 0.f;
        const float* wr = fcw + (size_t)t * H0;
        for (int k = 0; k < H0; k += 4) {
            float4 w = *(const float4*)(wr + k);
            a0 += w.x * fs[0][k] + w.y * fs[0][k+1] + w.z * fs[0][k+2] + w.w * fs[0][k+3];
            a1 += w.x * fs[1][k] + w.y * fs[1][k+1] + w.z * fs[1][k+2] + w.w * fs[1][k+3];
            a2 += w.x * fs[2][k] + w.y * fs[2][k+1] + w.z * fs[2][k+2] + w.w * fs[2][k+3];
            a3 += w.x * fs[3][k] + w.y * fs[3][k+1] + w.z * fs[3][k+2] + w.w * fs[3][k+3];
        }
        z[0][t] = a0; z[1][t] = a1; z[2][t] = a2; z[3][t] = a3;
    }
    __syncthreads();
    int lane = t & 63, wave = t >> 6;   // 2 waves, each handles 2 rows
    #pragma unroll
    for (int rr = 0; rr < 2; rr++) {
        int r = wave * 2 + rr;
        int row = row0 + r;
        float a = (lane < H1) ? z[r][lane] : 0.f;
        float b2 = (lane < H1 - 64) ? z[r][64 + lane] : 0.f;
        float s1 = a + b2, s2 = a * a + b2 * b2;
        #pragma unroll
        for (int s = 32; s > 0; s >>= 1) { s1 += __shfl_xor(s1, s); s2 += __shfl_xor(s2, s); }
        float mean = s1 / (float)H1;
        float var = s2 / (float)H1 - mean * mean;
        float inv = 1.0f / sqrtf(var + EPS_BN);
        float gamma, beta;
        if (row < U_NODES) { gamma = gu[row];            beta = bu[row]; }
        else               { gamma = gi[row - U_NODES];  beta = bi[row - U_NODES]; }
        if (lane < H1) {
            float v = gamma * (a - mean) * inv + beta;
            out[(size_t)row * H1 + lane] = v > 0.f ? v : 0.f;
        }
        if (lane < H1 - 64) {
            float v = gamma * (b2 - mean) * inv + beta;
            out[(size_t)row * H1 + 64 + lane] = v > 0.f ? v : 0.f;
        }
    }
}

extern "C" void kernel_launch(void* const* d_in, const int* in_sizes, int n_in,
                              void* d_out, int out_size, void* d_ws, size_t ws_size,
                              hipStream_t stream) {
    (void)in_sizes; (void)n_in; (void)out_size; (void)ws_size;
    const float* x         = (const float*)d_in[0];
    const float* basis     = (const float*)d_in[1];
    const float* comp      = (const float*)d_in[2];
    const float* root      = (const float*)d_in[3];
    const float* bias_rgcn = (const float*)d_in[4];
    const float* fc_w      = (const float*)d_in[5];
    const float* gu        = (const float*)d_in[6];
    const float* bu        = (const float*)d_in[7];
    const float* gi        = (const float*)d_in[8];
    const float* bi        = (const float*)d_in[9];
    const int*   ei        = (const int*)d_in[10];
    const int*   et        = (const int*)d_in[11];
    float* out = (float*)d_out;

    char* ws = (char*)d_ws;
    size_t off = 0;
    auto carve = [&](size_t bytes) -> void* {
        void* p = ws + off;
        off += (bytes + 255) & ~(size_t)255;
        return p;
    };
    ushort* xb      = (ushort*)carve((size_t)N_NODES * K_DIM * 2);
    ushort* wallT   = (ushort*)carve((size_t)M_PAD * K_DIM * 2);
    ushort* hall    = (ushort*)carve((size_t)N_NODES * M_COLS * 2);
    float*  feats   = (float*) carve((size_t)N_NODES * H0 * 4);
    int*    cnt     = (int*)   carve((size_t)NSEG * 4);
    int*    offs    = (int*)   carve((size_t)(NSEG + 1) * 4);
    int*    cursor  = (int*)   carve((size_t)NSEG * 4);
    int*    edge_val= (int*)   carve((size_t)E_EDGES * 4);
    float*  edge_w  = (float*) carve((size_t)E_EDGES * 4);

    k_convert_x<<<16384, 256, 0, stream>>>(x, xb, cnt);
    k_make_wallT<<<dim3(128, 16), 256, 0, stream>>>(basis, comp, root, wallT);
    k_count<<<E_EDGES / 256, 256, 0, stream>>>(ei, et, cnt);
    k_scan<<<1, 256, 0, stream>>>(cnt, offs, cursor);
    k_fill<<<E_EDGES / 256, 256, 0, stream>>>(ei, et, offs, cursor, edge_val, edge_w);
    k_gemm<<<768, 256, 0, stream>>>(xb, wallT, hall);
    k_agg<<<N_NODES, 128, 0, stream>>>(hall, offs, edge_val, edge_w, bias_rgcn, feats);
    k_fc_bn<<<N_NODES / 4, 128, 0, stream>>>(feats, fc_w, gu, bu, gi, bi, out);
}